// Round 1
// baseline (5487.440 us; speedup 1.0000x reference)
//
#include <hip/hip_runtime.h>

#define HD 32   // hidden/emb dim
#define ND 16   // node feature dim
#define ED 8    // edge feature dim

// ---------------------------------------------------------------------------
// Edge MLP, 40 inputs = [xt[t](16), xs[s](16), ea[e](8)], aggregate sum by t.
// ---------------------------------------------------------------------------
__global__ __launch_bounds__(256) void edge40_kernel(
    const int* __restrict__ src, const int* __restrict__ tgt,
    const float* __restrict__ xt,   // [n_t, 16]
    const float* __restrict__ xs,   // [n_s, 16]
    const float* __restrict__ ea,   // [nE, 8]
    const float* __restrict__ W1, const float* __restrict__ b1,   // [40,32],[32]
    const float* __restrict__ W2, const float* __restrict__ b2,   // [32,32],[32]
    float* __restrict__ aggr,       // [n_t, 32] (atomic sum)
    float* __restrict__ cnt,        // [n_t]
    int nE)
{
    __shared__ float sW1[40 * HD];
    __shared__ float sW2[HD * HD];
    __shared__ float sb1[HD], sb2[HD];
    for (int i = threadIdx.x; i < 40 * HD; i += 256) sW1[i] = W1[i];
    for (int i = threadIdx.x; i < HD * HD; i += 256) sW2[i] = W2[i];
    if (threadIdx.x < HD) { sb1[threadIdx.x] = b1[threadIdx.x]; sb2[threadIdx.x] = b2[threadIdx.x]; }
    __syncthreads();

    int e = blockIdx.x * 256 + threadIdx.x;
    if (e >= nE) return;
    int s = src[e], t = tgt[e];

    float in[40];
    const float4* xt4 = reinterpret_cast<const float4*>(xt + (size_t)t * ND);
    const float4* xs4 = reinterpret_cast<const float4*>(xs + (size_t)s * ND);
    const float4* ea4 = reinterpret_cast<const float4*>(ea + (size_t)e * ED);
#pragma unroll
    for (int q = 0; q < 4; q++) { float4 v = xt4[q]; in[4*q+0]=v.x; in[4*q+1]=v.y; in[4*q+2]=v.z; in[4*q+3]=v.w; }
#pragma unroll
    for (int q = 0; q < 4; q++) { float4 v = xs4[q]; in[16+4*q+0]=v.x; in[16+4*q+1]=v.y; in[16+4*q+2]=v.z; in[16+4*q+3]=v.w; }
#pragma unroll
    for (int q = 0; q < 2; q++) { float4 v = ea4[q]; in[32+4*q+0]=v.x; in[32+4*q+1]=v.y; in[32+4*q+2]=v.z; in[32+4*q+3]=v.w; }

    float hid[HD];
#pragma unroll 4
    for (int h = 0; h < HD; h++) {
        float acc = sb1[h];
#pragma unroll
        for (int i = 0; i < 40; i++) acc = fmaf(in[i], sW1[i * HD + h], acc);
        hid[h] = fmaxf(acc, 0.0f);
    }
    float* ob = aggr + (size_t)t * HD;
#pragma unroll 4
    for (int o = 0; o < HD; o++) {
        float acc = sb2[o];
#pragma unroll
        for (int h = 0; h < HD; h++) acc = fmaf(hid[h], sW2[h * HD + o], acc);
        atomicAdd(ob + o, acc);
    }
    atomicAdd(cnt + t, 1.0f);
}

// ---------------------------------------------------------------------------
// Edge MLP, 56 inputs = [xa[s](16), fv[t](32), ea[e](8)], aggregate sum by s.
// ---------------------------------------------------------------------------
__global__ __launch_bounds__(256) void edge56_kernel(
    const int* __restrict__ src, const int* __restrict__ tgt,
    const float* __restrict__ xa,   // [n_a, 16]
    const float* __restrict__ fv,   // [n_v, 32]
    const float* __restrict__ ea,   // [nE, 8]
    const float* __restrict__ W1, const float* __restrict__ b1,   // [56,32],[32]
    const float* __restrict__ W2, const float* __restrict__ b2,   // [32,32],[32]
    float* __restrict__ aggr,       // [n_a, 32] (atomic sum)
    float* __restrict__ cnt,        // [n_a]
    int nE)
{
    __shared__ float sW1[56 * HD];
    __shared__ float sW2[HD * HD];
    __shared__ float sb1[HD], sb2[HD];
    for (int i = threadIdx.x; i < 56 * HD; i += 256) sW1[i] = W1[i];
    for (int i = threadIdx.x; i < HD * HD; i += 256) sW2[i] = W2[i];
    if (threadIdx.x < HD) { sb1[threadIdx.x] = b1[threadIdx.x]; sb2[threadIdx.x] = b2[threadIdx.x]; }
    __syncthreads();

    int e = blockIdx.x * 256 + threadIdx.x;
    if (e >= nE) return;
    int s = src[e], t = tgt[e];

    float in[56];
    const float4* xa4 = reinterpret_cast<const float4*>(xa + (size_t)s * ND);
    const float4* fv4 = reinterpret_cast<const float4*>(fv + (size_t)t * HD);
    const float4* ea4 = reinterpret_cast<const float4*>(ea + (size_t)e * ED);
#pragma unroll
    for (int q = 0; q < 4; q++) { float4 v = xa4[q]; in[4*q+0]=v.x; in[4*q+1]=v.y; in[4*q+2]=v.z; in[4*q+3]=v.w; }
#pragma unroll
    for (int q = 0; q < 8; q++) { float4 v = fv4[q]; in[16+4*q+0]=v.x; in[16+4*q+1]=v.y; in[16+4*q+2]=v.z; in[16+4*q+3]=v.w; }
#pragma unroll
    for (int q = 0; q < 2; q++) { float4 v = ea4[q]; in[48+4*q+0]=v.x; in[48+4*q+1]=v.y; in[48+4*q+2]=v.z; in[48+4*q+3]=v.w; }

    float hid[HD];
#pragma unroll 4
    for (int h = 0; h < HD; h++) {
        float acc = sb1[h];
#pragma unroll
        for (int i = 0; i < 56; i++) acc = fmaf(in[i], sW1[i * HD + h], acc);
        hid[h] = fmaxf(acc, 0.0f);
    }
    float* ob = aggr + (size_t)s * HD;
#pragma unroll 4
    for (int o = 0; o < HD; o++) {
        float acc = sb2[o];
#pragma unroll
        for (int h = 0; h < HD; h++) acc = fmaf(hid[h], sW2[h * HD + o], acc);
        atomicAdd(ob + o, acc);
    }
    atomicAdd(cnt + s, 1.0f);
}

// ---------------------------------------------------------------------------
// Variable-node MLP: in = [x_v(16), mean_g(32), mean_h(32)] -> f_v [n,32]
// ---------------------------------------------------------------------------
__global__ __launch_bounds__(256) void fv_kernel(
    const float* __restrict__ xv,
    const float* __restrict__ aggr_g, const float* __restrict__ cnt_g,
    const float* __restrict__ aggr_h, const float* __restrict__ cnt_h,
    const float* __restrict__ W1, const float* __restrict__ b1,   // [80,32],[32]
    const float* __restrict__ W2, const float* __restrict__ b2,   // [32,32],[32]
    float* __restrict__ out, int n)
{
    __shared__ float sW1[80 * HD];
    __shared__ float sW2[HD * HD];
    __shared__ float sb1[HD], sb2[HD];
    for (int i = threadIdx.x; i < 80 * HD; i += 256) sW1[i] = W1[i];
    for (int i = threadIdx.x; i < HD * HD; i += 256) sW2[i] = W2[i];
    if (threadIdx.x < HD) { sb1[threadIdx.x] = b1[threadIdx.x]; sb2[threadIdx.x] = b2[threadIdx.x]; }
    __syncthreads();

    int v = blockIdx.x * 256 + threadIdx.x;
    if (v >= n) return;

    float in[80];
    const float4* xv4 = reinterpret_cast<const float4*>(xv + (size_t)v * ND);
#pragma unroll
    for (int q = 0; q < 4; q++) { float4 t = xv4[q]; in[4*q+0]=t.x; in[4*q+1]=t.y; in[4*q+2]=t.z; in[4*q+3]=t.w; }
    float invg = 1.0f / fmaxf(cnt_g[v], 1.0f);
    float invh = 1.0f / fmaxf(cnt_h[v], 1.0f);
    const float4* g4 = reinterpret_cast<const float4*>(aggr_g + (size_t)v * HD);
    const float4* h4 = reinterpret_cast<const float4*>(aggr_h + (size_t)v * HD);
#pragma unroll
    for (int q = 0; q < 8; q++) { float4 t = g4[q]; in[16+4*q+0]=t.x*invg; in[16+4*q+1]=t.y*invg; in[16+4*q+2]=t.z*invg; in[16+4*q+3]=t.w*invg; }
#pragma unroll
    for (int q = 0; q < 8; q++) { float4 t = h4[q]; in[48+4*q+0]=t.x*invh; in[48+4*q+1]=t.y*invh; in[48+4*q+2]=t.z*invh; in[48+4*q+3]=t.w*invh; }

    float hid[HD];
#pragma unroll 4
    for (int h = 0; h < HD; h++) {
        float acc = sb1[h];
#pragma unroll
        for (int i = 0; i < 80; i++) acc = fmaf(in[i], sW1[i * HD + h], acc);
        hid[h] = fmaxf(acc, 0.0f);
    }
    float* ob = out + (size_t)v * HD;
#pragma unroll 4
    for (int o = 0; o < HD; o++) {
        float acc = sb2[o];
#pragma unroll
        for (int h = 0; h < HD; h++) acc = fmaf(hid[h], sW2[h * HD + o], acc);
        ob[o] = acc;
    }
}

// ---------------------------------------------------------------------------
// Cut-node MLP: in = [x_a(16), mean_ga(32)] -> out [n,32]
// ---------------------------------------------------------------------------
__global__ __launch_bounds__(256) void fa_kernel(
    const float* __restrict__ xa,
    const float* __restrict__ aggr, const float* __restrict__ cnt,
    const float* __restrict__ W1, const float* __restrict__ b1,   // [48,32],[32]
    const float* __restrict__ W2, const float* __restrict__ b2,   // [32,32],[32]
    float* __restrict__ out, int n)
{
    __shared__ float sW1[48 * HD];
    __shared__ float sW2[HD * HD];
    __shared__ float sb1[HD], sb2[HD];
    for (int i = threadIdx.x; i < 48 * HD; i += 256) sW1[i] = W1[i];
    for (int i = threadIdx.x; i < HD * HD; i += 256) sW2[i] = W2[i];
    if (threadIdx.x < HD) { sb1[threadIdx.x] = b1[threadIdx.x]; sb2[threadIdx.x] = b2[threadIdx.x]; }
    __syncthreads();

    int a = blockIdx.x * 256 + threadIdx.x;
    if (a >= n) return;

    float in[48];
    const float4* xa4 = reinterpret_cast<const float4*>(xa + (size_t)a * ND);
#pragma unroll
    for (int q = 0; q < 4; q++) { float4 t = xa4[q]; in[4*q+0]=t.x; in[4*q+1]=t.y; in[4*q+2]=t.z; in[4*q+3]=t.w; }
    float inv = 1.0f / fmaxf(cnt[a], 1.0f);
    const float4* g4 = reinterpret_cast<const float4*>(aggr + (size_t)a * HD);
#pragma unroll
    for (int q = 0; q < 8; q++) { float4 t = g4[q]; in[16+4*q+0]=t.x*inv; in[16+4*q+1]=t.y*inv; in[16+4*q+2]=t.z*inv; in[16+4*q+3]=t.w*inv; }

    float hid[HD];
#pragma unroll 4
    for (int h = 0; h < HD; h++) {
        float acc = sb1[h];
#pragma unroll
        for (int i = 0; i < 48; i++) acc = fmaf(in[i], sW1[i * HD + h], acc);
        hid[h] = fmaxf(acc, 0.0f);
    }
    float* ob = out + (size_t)a * HD;
#pragma unroll 4
    for (int o = 0; o < HD; o++) {
        float acc = sb2[o];
#pragma unroll
        for (int h = 0; h < HD; h++) acc = fmaf(hid[h], sW2[h * HD + o], acc);
        ob[o] = acc;
    }
}

extern "C" void kernel_launch(void* const* d_in, const int* in_sizes, int n_in,
                              void* d_out, int out_size, void* d_ws, size_t ws_size,
                              hipStream_t stream) {
    const float* x_c    = (const float*)d_in[0];
    const float* x_v    = (const float*)d_in[1];
    const float* x_a    = (const float*)d_in[2];
    const int*   ei_c2v = (const int*)d_in[3];
    const int*   ei_a2v = (const int*)d_in[4];
    const float* ea_c2v = (const float*)d_in[5];
    const float* ea_a2v = (const float*)d_in[6];
    const float *gv_W1=(const float*)d_in[7],  *gv_b1=(const float*)d_in[8],
                *gv_W2=(const float*)d_in[9],  *gv_b2=(const float*)d_in[10];
    const float *hv_W1=(const float*)d_in[11], *hv_b1=(const float*)d_in[12],
                *hv_W2=(const float*)d_in[13], *hv_b2=(const float*)d_in[14];
    const float *fv_W1=(const float*)d_in[15], *fv_b1=(const float*)d_in[16],
                *fv_W2=(const float*)d_in[17], *fv_b2=(const float*)d_in[18];
    const float *ga_W1=(const float*)d_in[19], *ga_b1=(const float*)d_in[20],
                *ga_W2=(const float*)d_in[21], *ga_b2=(const float*)d_in[22];
    const float *fa_W1=(const float*)d_in[23], *fa_b1=(const float*)d_in[24],
                *fa_W2=(const float*)d_in[25], *fa_b2=(const float*)d_in[26];

    const int NC = in_sizes[0] / ND;
    const int NV = in_sizes[1] / ND;
    const int NA = in_sizes[2] / ND;
    const int EC = in_sizes[3] / 2;
    const int EA = in_sizes[4] / 2;
    (void)NC; (void)n_in; (void)ws_size; (void)out_size;

    // Workspace layout (floats)
    float* ws = (float*)d_ws;
    size_t off = 0;
    float* aggr_g  = ws + off; off += (size_t)NV * HD;
    float* aggr_h  = ws + off; off += (size_t)NV * HD;
    float* aggr_ga = ws + off; off += (size_t)NA * HD;
    float* cnt_g   = ws + off; off += (size_t)NV;
    float* cnt_h   = ws + off; off += (size_t)NV;
    float* cnt_ga  = ws + off; off += (size_t)NA;
    size_t zero_bytes = off * sizeof(float);
    float* f_v     = ws + off; off += (size_t)NV * HD;

    hipMemsetAsync(d_ws, 0, zero_bytes, stream);

    // c2v edges: g_v
    edge40_kernel<<<(EC + 255) / 256, 256, 0, stream>>>(
        ei_c2v, ei_c2v + EC, x_v, x_c, ea_c2v,
        gv_W1, gv_b1, gv_W2, gv_b2, aggr_g, cnt_g, EC);

    // a2v edges: h_v
    edge40_kernel<<<(EA + 255) / 256, 256, 0, stream>>>(
        ei_a2v, ei_a2v + EA, x_v, x_a, ea_a2v,
        hv_W1, hv_b1, hv_W2, hv_b2, aggr_h, cnt_h, EA);

    // f_v
    fv_kernel<<<(NV + 255) / 256, 256, 0, stream>>>(
        x_v, aggr_g, cnt_g, aggr_h, cnt_h,
        fv_W1, fv_b1, fv_W2, fv_b2, f_v, NV);

    // a2v edges (reverse): g_a
    edge56_kernel<<<(EA + 255) / 256, 256, 0, stream>>>(
        ei_a2v, ei_a2v + EA, x_a, f_v, ea_a2v,
        ga_W1, ga_b1, ga_W2, ga_b2, aggr_ga, cnt_ga, EA);

    // f_a -> output
    fa_kernel<<<(NA + 255) / 256, 256, 0, stream>>>(
        x_a, aggr_ga, cnt_ga,
        fa_W1, fa_b1, fa_W2, fa_b2, (float*)d_out, NA);
}

// Round 2
// 2120.677 us; speedup vs baseline: 2.5876x; 2.5876x over previous
//
#include <hip/hip_runtime.h>

#define HD 32   // hidden/emb dim
#define ND 16   // node feature dim
#define ED 8    // edge feature dim

// ===========================================================================
// CSR build: histogram -> exclusive scan (3 arrays, one block each) -> scatter
// ===========================================================================
__global__ __launch_bounds__(256) void hist_kernel(
    const int* __restrict__ keys, int* __restrict__ deg, int n)
{
    int i = blockIdx.x * 256 + threadIdx.x;
    if (i < n) atomicAdd(&deg[keys[i]], 1);
}

__device__ __forceinline__ void scan_one(const int* __restrict__ deg,
                                         int* __restrict__ off,
                                         int* __restrict__ cur, int n)
{
    __shared__ int wsum[16];
    __shared__ int sbase, schunk;
    if (threadIdx.x == 0) sbase = 0;
    __syncthreads();
    int lane = threadIdx.x & 63;
    int wid  = threadIdx.x >> 6;
    for (int start = 0; start < n; start += 1024) {
        int i = start + (int)threadIdx.x;
        int v = (i < n) ? deg[i] : 0;
        int x = v;
#pragma unroll
        for (int dd = 1; dd < 64; dd <<= 1) {
            int y = __shfl_up(x, dd, 64);
            if (lane >= dd) x += y;
        }
        if (lane == 63) wsum[wid] = x;
        __syncthreads();
        if (threadIdx.x == 0) {
            int a2 = 0;
#pragma unroll
            for (int w = 0; w < 16; w++) { int t = wsum[w]; wsum[w] = a2; a2 += t; }
            schunk = a2;
        }
        __syncthreads();
        int excl = sbase + wsum[wid] + (x - v);
        if (i < n) { off[i] = excl; cur[i] = excl; }
        __syncthreads();
        if (threadIdx.x == 0) sbase += schunk;
        __syncthreads();
    }
}

__global__ __launch_bounds__(1024) void scan3_kernel(
    const int* d0, int* o0, int* c0, int n0,
    const int* d1, int* o1, int* c1, int n1,
    const int* d2, int* o2, int* c2, int n2)
{
    if (blockIdx.x == 0)      scan_one(d0, o0, c0, n0);
    else if (blockIdx.x == 1) scan_one(d1, o1, c1, n1);
    else                      scan_one(d2, o2, c2, n2);
}

__global__ __launch_bounds__(256) void scatter_kernel(
    const int* __restrict__ keys, int* __restrict__ cur,
    int* __restrict__ csr, int n)
{
    int i = blockIdx.x * 256 + threadIdx.x;
    if (i < n) {
        int p = atomicAdd(&cur[keys[i]], 1);
        csr[p] = i;
    }
}

// ===========================================================================
// Fused variable-node kernel: one thread per v node.
//   mean_g over c2v edges (gv MLP), mean_h over a2v edges (hv MLP),
//   then f_v = fv MLP([x_v, mean_g, mean_h]).
// Weights read with wave-uniform indices from global -> scalar (s_load) path.
// Layer-2 hoisted: mean(relu(.)W2 + b2) = (sum relu)W2/c + b2.
// ===========================================================================
__global__ __launch_bounds__(256) void fv_fused_kernel(
    const float* __restrict__ xv, const float* __restrict__ xc,
    const float* __restrict__ xa,
    const int* __restrict__ c2v_src, const int* __restrict__ a2v_src,
    const float* __restrict__ ea_c, const float* __restrict__ ea_a,
    const int* __restrict__ off_g, const int* __restrict__ deg_g, const int* __restrict__ csr_g,
    const int* __restrict__ off_h, const int* __restrict__ deg_h, const int* __restrict__ csr_h,
    const float* __restrict__ gvW1, const float* __restrict__ gvb1,
    const float* __restrict__ gvW2, const float* __restrict__ gvb2,
    const float* __restrict__ hvW1, const float* __restrict__ hvb1,
    const float* __restrict__ hvW2, const float* __restrict__ hvb2,
    const float* __restrict__ fvW1, const float* __restrict__ fvb1,
    const float* __restrict__ fvW2, const float* __restrict__ fvb2,
    float* __restrict__ fv, int nV)
{
    int v = blockIdx.x * 256 + threadIdx.x;
    if (v >= nV) return;

    float in80[80];
    {
        const float4* p = reinterpret_cast<const float4*>(xv + (size_t)v * ND);
#pragma unroll
        for (int q = 0; q < 4; q++) {
            float4 t = p[q];
            in80[4*q+0] = t.x; in80[4*q+1] = t.y; in80[4*q+2] = t.z; in80[4*q+3] = t.w;
        }
    }

    float acc[HD];

    // ---------- g: c2v edges grouped by target v ----------
#pragma unroll
    for (int h = 0; h < HD; h++) acc[h] = 0.0f;
    {
        int base = off_g[v], d = deg_g[v];
        for (int k = 0; k < d; k++) {
            int e = csr_g[base + k];
            int s = c2v_src[e];
            float xs[ND], ee[ED];
            {
                const float4* p = reinterpret_cast<const float4*>(xc + (size_t)s * ND);
#pragma unroll
                for (int q = 0; q < 4; q++) {
                    float4 t = p[q];
                    xs[4*q+0] = t.x; xs[4*q+1] = t.y; xs[4*q+2] = t.z; xs[4*q+3] = t.w;
                }
                const float4* pe = reinterpret_cast<const float4*>(ea_c + (size_t)e * ED);
#pragma unroll
                for (int q = 0; q < 2; q++) {
                    float4 t = pe[q];
                    ee[4*q+0] = t.x; ee[4*q+1] = t.y; ee[4*q+2] = t.z; ee[4*q+3] = t.w;
                }
            }
#pragma unroll
            for (int h = 0; h < HD; h++) {
                float t = gvb1[h];
#pragma unroll
                for (int i = 0; i < ND; i++) t = fmaf(in80[i], gvW1[i * HD + h], t);
#pragma unroll
                for (int i = 0; i < ND; i++) t = fmaf(xs[i], gvW1[(ND + i) * HD + h], t);
#pragma unroll
                for (int i = 0; i < ED; i++) t = fmaf(ee[i], gvW1[(2 * ND + i) * HD + h], t);
                acc[h] += fmaxf(t, 0.0f);
            }
        }
        float fd = (float)d;
        float invd = 1.0f / fmaxf(fd, 1.0f);
#pragma unroll
        for (int o = 0; o < HD; o++) {
            float t = fd * gvb2[o];
#pragma unroll
            for (int h = 0; h < HD; h++) t = fmaf(acc[h], gvW2[h * HD + o], t);
            in80[ND + o] = t * invd;
        }
    }

    // ---------- h: a2v edges grouped by target v ----------
#pragma unroll
    for (int h = 0; h < HD; h++) acc[h] = 0.0f;
    {
        int base = off_h[v], d = deg_h[v];
        for (int k = 0; k < d; k++) {
            int e = csr_h[base + k];
            int s = a2v_src[e];
            float xs[ND], ee[ED];
            {
                const float4* p = reinterpret_cast<const float4*>(xa + (size_t)s * ND);
#pragma unroll
                for (int q = 0; q < 4; q++) {
                    float4 t = p[q];
                    xs[4*q+0] = t.x; xs[4*q+1] = t.y; xs[4*q+2] = t.z; xs[4*q+3] = t.w;
                }
                const float4* pe = reinterpret_cast<const float4*>(ea_a + (size_t)e * ED);
#pragma unroll
                for (int q = 0; q < 2; q++) {
                    float4 t = pe[q];
                    ee[4*q+0] = t.x; ee[4*q+1] = t.y; ee[4*q+2] = t.z; ee[4*q+3] = t.w;
                }
            }
#pragma unroll
            for (int h = 0; h < HD; h++) {
                float t = hvb1[h];
#pragma unroll
                for (int i = 0; i < ND; i++) t = fmaf(in80[i], hvW1[i * HD + h], t);
#pragma unroll
                for (int i = 0; i < ND; i++) t = fmaf(xs[i], hvW1[(ND + i) * HD + h], t);
#pragma unroll
                for (int i = 0; i < ED; i++) t = fmaf(ee[i], hvW1[(2 * ND + i) * HD + h], t);
                acc[h] += fmaxf(t, 0.0f);
            }
        }
        float fd = (float)d;
        float invd = 1.0f / fmaxf(fd, 1.0f);
#pragma unroll
        for (int o = 0; o < HD; o++) {
            float t = fd * hvb2[o];
#pragma unroll
            for (int h = 0; h < HD; h++) t = fmaf(acc[h], hvW2[h * HD + o], t);
            in80[ND + HD + o] = t * invd;
        }
    }

    // ---------- fv MLP: [x_v, mean_g, mean_h] (80) -> 32 ----------
    float hid[HD];
#pragma unroll
    for (int h = 0; h < HD; h++) {
        float t = fvb1[h];
#pragma unroll
        for (int i = 0; i < 80; i++) t = fmaf(in80[i], fvW1[i * HD + h], t);
        hid[h] = fmaxf(t, 0.0f);
    }
    float* ob = fv + (size_t)v * HD;
#pragma unroll
    for (int o = 0; o < HD; o++) {
        float t = fvb2[o];
#pragma unroll
        for (int h = 0; h < HD; h++) t = fmaf(hid[h], fvW2[h * HD + o], t);
        ob[o] = t;
    }
}

// ===========================================================================
// Fused cut-node kernel: 32 lanes per a node (avg degree ~160).
//   mean_ga over a2v edges grouped by source a (ga MLP, layer-2 hoisted),
//   butterfly-reduce partial hidden sums across 32 lanes,
//   then f_a = fa MLP([x_a, mean_ga]); lane j writes output element j.
// ===========================================================================
__global__ __launch_bounds__(256) void ga_fused_kernel(
    const float* __restrict__ xa, const float* __restrict__ fvv,
    const float* __restrict__ ea_a,
    const int* __restrict__ a2v_tgt,
    const int* __restrict__ off_a, const int* __restrict__ deg_a, const int* __restrict__ csr_a,
    const float* __restrict__ gaW1, const float* __restrict__ gab1,
    const float* __restrict__ gaW2, const float* __restrict__ gab2,
    const float* __restrict__ faW1, const float* __restrict__ fab1,
    const float* __restrict__ faW2, const float* __restrict__ fab2,
    float* __restrict__ out, int nA)
{
    int gid  = blockIdx.x * 256 + threadIdx.x;
    int a    = gid >> 5;
    int lane = gid & 31;
    if (a >= nA) return;

    float xar[ND];
    {
        const float4* p = reinterpret_cast<const float4*>(xa + (size_t)a * ND);
#pragma unroll
        for (int q = 0; q < 4; q++) {
            float4 t = p[q];
            xar[4*q+0] = t.x; xar[4*q+1] = t.y; xar[4*q+2] = t.z; xar[4*q+3] = t.w;
        }
    }

    float acc[HD];
#pragma unroll
    for (int h = 0; h < HD; h++) acc[h] = 0.0f;

    int base = off_a[a], d = deg_a[a];
    for (int k = lane; k < d; k += 32) {
        int e = csr_a[base + k];
        int t = a2v_tgt[e];
        float fvt[HD], ee[ED];
        {
            const float4* p = reinterpret_cast<const float4*>(fvv + (size_t)t * HD);
#pragma unroll
            for (int q = 0; q < 8; q++) {
                float4 w = p[q];
                fvt[4*q+0] = w.x; fvt[4*q+1] = w.y; fvt[4*q+2] = w.z; fvt[4*q+3] = w.w;
            }
            const float4* pe = reinterpret_cast<const float4*>(ea_a + (size_t)e * ED);
#pragma unroll
            for (int q = 0; q < 2; q++) {
                float4 w = pe[q];
                ee[4*q+0] = w.x; ee[4*q+1] = w.y; ee[4*q+2] = w.z; ee[4*q+3] = w.w;
            }
        }
#pragma unroll
        for (int h = 0; h < HD; h++) {
            float s = gab1[h];
#pragma unroll
            for (int i = 0; i < ND; i++) s = fmaf(xar[i], gaW1[i * HD + h], s);
#pragma unroll
            for (int i = 0; i < HD; i++) s = fmaf(fvt[i], gaW1[(ND + i) * HD + h], s);
#pragma unroll
            for (int i = 0; i < ED; i++) s = fmaf(ee[i], gaW1[(ND + HD + i) * HD + h], s);
            acc[h] += fmaxf(s, 0.0f);
        }
    }

    // reduce partial hidden sums across the 32 lanes of this node
#pragma unroll
    for (int m = 16; m >= 1; m >>= 1) {
#pragma unroll
        for (int h = 0; h < HD; h++) acc[h] += __shfl_xor(acc[h], m, 32);
    }

    float fd = (float)d;
    float invd = 1.0f / fmaxf(fd, 1.0f);
    float in48[ND + HD];
#pragma unroll
    for (int i = 0; i < ND; i++) in48[i] = xar[i];
#pragma unroll
    for (int o = 0; o < HD; o++) {
        float t = fd * gab2[o];
#pragma unroll
        for (int h = 0; h < HD; h++) t = fmaf(acc[h], gaW2[h * HD + o], t);
        in48[ND + o] = t * invd;
    }

    // fa MLP hidden (redundant across the 32 lanes; inputs identical)
    float hid[HD];
#pragma unroll
    for (int h = 0; h < HD; h++) {
        float t = fab1[h];
#pragma unroll
        for (int i = 0; i < ND + HD; i++) t = fmaf(in48[i], faW1[i * HD + h], t);
        hid[h] = fmaxf(t, 0.0f);
    }
    // each lane computes and writes its own output element
    float o = fab2[lane];
#pragma unroll
    for (int h = 0; h < HD; h++) o = fmaf(hid[h], faW2[h * HD + lane], o);
    out[(size_t)a * HD + lane] = o;
}

// ===========================================================================
extern "C" void kernel_launch(void* const* d_in, const int* in_sizes, int n_in,
                              void* d_out, int out_size, void* d_ws, size_t ws_size,
                              hipStream_t stream) {
    const float* x_c    = (const float*)d_in[0];
    const float* x_v    = (const float*)d_in[1];
    const float* x_a    = (const float*)d_in[2];
    const int*   ei_c2v = (const int*)d_in[3];
    const int*   ei_a2v = (const int*)d_in[4];
    const float* ea_c2v = (const float*)d_in[5];
    const float* ea_a2v = (const float*)d_in[6];
    const float *gv_W1=(const float*)d_in[7],  *gv_b1=(const float*)d_in[8],
                *gv_W2=(const float*)d_in[9],  *gv_b2=(const float*)d_in[10];
    const float *hv_W1=(const float*)d_in[11], *hv_b1=(const float*)d_in[12],
                *hv_W2=(const float*)d_in[13], *hv_b2=(const float*)d_in[14];
    const float *fv_W1=(const float*)d_in[15], *fv_b1=(const float*)d_in[16],
                *fv_W2=(const float*)d_in[17], *fv_b2=(const float*)d_in[18];
    const float *ga_W1=(const float*)d_in[19], *ga_b1=(const float*)d_in[20],
                *ga_W2=(const float*)d_in[21], *ga_b2=(const float*)d_in[22];
    const float *fa_W1=(const float*)d_in[23], *fa_b1=(const float*)d_in[24],
                *fa_W2=(const float*)d_in[25], *fa_b2=(const float*)d_in[26];

    const int NV = in_sizes[1] / ND;
    const int NA = in_sizes[2] / ND;
    const int EC = in_sizes[3] / 2;
    const int EA = in_sizes[4] / 2;
    (void)n_in; (void)ws_size; (void)out_size;

    const int* c2v_s = ei_c2v;            // cut/constraint side of c2v
    const int* c2v_t = ei_c2v + EC;       // variable side
    const int* a2v_s = ei_a2v;            // cut node side
    const int* a2v_t = ei_a2v + EA;       // variable side

    // Workspace layout (4B words)
    int* wsI = (int*)d_ws;
    int* deg_g = wsI;                 // NV
    int* deg_h = deg_g + NV;          // NV
    int* deg_a = deg_h + NV;          // NA
    int* off_g = deg_a + NA;          // NV
    int* off_h = off_g + NV;          // NV
    int* off_a = off_h + NV;          // NA
    int* cur_g = off_a + NA;          // NV
    int* cur_h = cur_g + NV;          // NV
    int* cur_a = cur_h + NV;          // NA
    int* csr_g = cur_a + NA;          // EC
    int* csr_h = csr_g + EC;          // EA
    int* csr_a = csr_h + EA;          // EA
    float* f_v = (float*)(csr_a + EA);   // NV*HD

    // zero the degree histograms only
    hipMemsetAsync(deg_g, 0, (size_t)(2 * NV + NA) * sizeof(int), stream);

    // histograms
    hist_kernel<<<(EC + 255) / 256, 256, 0, stream>>>(c2v_t, deg_g, EC);
    hist_kernel<<<(EA + 255) / 256, 256, 0, stream>>>(a2v_t, deg_h, EA);
    hist_kernel<<<(EA + 255) / 256, 256, 0, stream>>>(a2v_s, deg_a, EA);

    // exclusive scans (3 arrays, 1 block each)
    scan3_kernel<<<3, 1024, 0, stream>>>(deg_g, off_g, cur_g, NV,
                                         deg_h, off_h, cur_h, NV,
                                         deg_a, off_a, cur_a, NA);

    // scatter edge ids into CSR
    scatter_kernel<<<(EC + 255) / 256, 256, 0, stream>>>(c2v_t, cur_g, csr_g, EC);
    scatter_kernel<<<(EA + 255) / 256, 256, 0, stream>>>(a2v_t, cur_h, csr_h, EA);
    scatter_kernel<<<(EA + 255) / 256, 256, 0, stream>>>(a2v_s, cur_a, csr_a, EA);

    // fused variable-node update -> f_v
    fv_fused_kernel<<<(NV + 255) / 256, 256, 0, stream>>>(
        x_v, x_c, x_a, c2v_s, a2v_s, ea_c2v, ea_a2v,
        off_g, deg_g, csr_g, off_h, deg_h, csr_h,
        gv_W1, gv_b1, gv_W2, gv_b2,
        hv_W1, hv_b1, hv_W2, hv_b2,
        fv_W1, fv_b1, fv_W2, fv_b2,
        f_v, NV);

    // fused cut-node update -> output
    ga_fused_kernel<<<(NA * 32 + 255) / 256, 256, 0, stream>>>(
        x_a, f_v, ea_a2v, a2v_t,
        off_a, deg_a, csr_a,
        ga_W1, ga_b1, ga_W2, ga_b2,
        fa_W1, fa_b1, fa_W2, fa_b2,
        (float*)d_out, NA);
}

// Round 3
// 1154.352 us; speedup vs baseline: 4.7537x; 1.8371x over previous
//
#include <hip/hip_runtime.h>

#define HD 32   // hidden/emb dim
#define ND 16   // node feature dim
#define ED 8    // edge feature dim

// ===========================================================================
// CSR build: histogram -> exclusive scan (3 arrays, one block each) -> scatter
// ===========================================================================
__global__ __launch_bounds__(256) void hist_kernel(
    const int* __restrict__ keys, int* __restrict__ deg, int n)
{
    int i = blockIdx.x * 256 + threadIdx.x;
    if (i < n) atomicAdd(&deg[keys[i]], 1);
}

__device__ __forceinline__ void scan_one(const int* __restrict__ deg,
                                         int* __restrict__ off,
                                         int* __restrict__ cur, int n)
{
    __shared__ int wsum[16];
    __shared__ int sbase, schunk;
    if (threadIdx.x == 0) sbase = 0;
    __syncthreads();
    int lane = threadIdx.x & 63;
    int wid  = threadIdx.x >> 6;
    for (int start = 0; start < n; start += 1024) {
        int i = start + (int)threadIdx.x;
        int v = (i < n) ? deg[i] : 0;
        int x = v;
#pragma unroll
        for (int dd = 1; dd < 64; dd <<= 1) {
            int y = __shfl_up(x, dd, 64);
            if (lane >= dd) x += y;
        }
        if (lane == 63) wsum[wid] = x;
        __syncthreads();
        if (threadIdx.x == 0) {
            int a2 = 0;
#pragma unroll
            for (int w = 0; w < 16; w++) { int t = wsum[w]; wsum[w] = a2; a2 += t; }
            schunk = a2;
        }
        __syncthreads();
        int excl = sbase + wsum[wid] + (x - v);
        if (i < n) { off[i] = excl; cur[i] = excl; }
        __syncthreads();
        if (threadIdx.x == 0) sbase += schunk;
        __syncthreads();
    }
}

__global__ __launch_bounds__(1024) void scan3_kernel(
    const int* d0, int* o0, int* c0, int n0,
    const int* d1, int* o1, int* c1, int n1,
    const int* d2, int* o2, int* c2, int n2)
{
    if (blockIdx.x == 0)      scan_one(d0, o0, c0, n0);
    else if (blockIdx.x == 1) scan_one(d1, o1, c1, n1);
    else                      scan_one(d2, o2, c2, n2);
}

__global__ __launch_bounds__(256) void scatter_kernel(
    const int* __restrict__ keys, int* __restrict__ cur,
    int* __restrict__ csr, int n)
{
    int i = blockIdx.x * 256 + threadIdx.x;
    if (i < n) {
        int p = atomicAdd(&cur[keys[i]], 1);
        csr[p] = i;
    }
}

// ===========================================================================
// Precompute folded layer-2 matrices:
//   Mg[c][h]  = sum_o gvW2[c][o] * fvW1[16+o][h]   bg[h] = sum_o gvb2[o]*fvW1[16+o][h]
//   Mh[c][h]  = sum_o hvW2[c][o] * fvW1[48+o][h]   bh[h] = sum_o hvb2[o]*fvW1[48+o][h]
//   Mga[c][h] = sum_o gaW2[c][o] * faW1[16+o][h]   bga[h]= sum_o gab2[o]*faW1[16+o][h]
// ===========================================================================
__global__ __launch_bounds__(256) void precomp_kernel(
    const float* __restrict__ gvW2, const float* __restrict__ gvb2,
    const float* __restrict__ hvW2, const float* __restrict__ hvb2,
    const float* __restrict__ gaW2, const float* __restrict__ gab2,
    const float* __restrict__ fvW1, const float* __restrict__ faW1,
    float* __restrict__ Mg, float* __restrict__ bg,
    float* __restrict__ Mh, float* __restrict__ bh,
    float* __restrict__ Mga, float* __restrict__ bga)
{
    int t = threadIdx.x;
    for (int idx = t; idx < HD * HD; idx += 256) {
        int c = idx >> 5, h = idx & 31;
        float sg = 0.f, sh = 0.f, sa = 0.f;
#pragma unroll
        for (int o = 0; o < HD; o++) {
            sg = fmaf(gvW2[c * HD + o], fvW1[(ND + o) * HD + h], sg);
            sh = fmaf(hvW2[c * HD + o], fvW1[(ND + HD + o) * HD + h], sh);
            sa = fmaf(gaW2[c * HD + o], faW1[(ND + o) * HD + h], sa);
        }
        Mg[idx] = sg; Mh[idx] = sh; Mga[idx] = sa;
    }
    if (t < HD) {
        float sg = 0.f, sh = 0.f, sa = 0.f;
#pragma unroll
        for (int o = 0; o < HD; o++) {
            sg = fmaf(gvb2[o], fvW1[(ND + o) * HD + t], sg);
            sh = fmaf(hvb2[o], fvW1[(ND + HD + o) * HD + t], sh);
            sa = fmaf(gab2[o], faW1[(ND + o) * HD + t], sa);
        }
        bg[t] = sg; bh[t] = sh; bga[t] = sa;
    }
}

// ===========================================================================
// fv edge kernel: 8 lanes per variable node, edge-split.
// Computes Ag[v][32] = sum_{c2v edges->v} relu(gv layer1) and
//          Ah[v][32] = sum_{a2v edges->v} relu(hv layer1).
// ===========================================================================
__global__ __launch_bounds__(256) void fv_edge_kernel(
    const float* __restrict__ xv, const float* __restrict__ xc,
    const float* __restrict__ xa,
    const int* __restrict__ c2v_src, const int* __restrict__ a2v_src,
    const float* __restrict__ ea_c, const float* __restrict__ ea_a,
    const int* __restrict__ off_g, const int* __restrict__ deg_g, const int* __restrict__ csr_g,
    const int* __restrict__ off_h, const int* __restrict__ deg_h, const int* __restrict__ csr_h,
    const float* __restrict__ gvW1, const float* __restrict__ gvb1,
    const float* __restrict__ hvW1, const float* __restrict__ hvb1,
    float* __restrict__ Ag, float* __restrict__ Ah, int nV)
{
    int gid = blockIdx.x * 256 + threadIdx.x;
    int v   = gid >> 3;
    int sub = threadIdx.x & 7;
    if (v >= nV) return;

    float xvr[ND];
    {
        const float4* p = reinterpret_cast<const float4*>(xv + (size_t)v * ND);
#pragma unroll
        for (int q = 0; q < 4; q++) {
            float4 t = p[q];
            xvr[4*q+0] = t.x; xvr[4*q+1] = t.y; xvr[4*q+2] = t.z; xvr[4*q+3] = t.w;
        }
    }

    float acc[HD];

    // ---------------- g: c2v edges ----------------
#pragma unroll
    for (int h = 0; h < HD; h++) acc[h] = 0.f;
    {
        int base = off_g[v], d = deg_g[v];
        for (int k = sub; k < d; k += 8) {
            int e = csr_g[base + k];
            int s = c2v_src[e];
            float xs[ND], ee[ED];
            {
                const float4* p = reinterpret_cast<const float4*>(xc + (size_t)s * ND);
#pragma unroll
                for (int q = 0; q < 4; q++) {
                    float4 t = p[q];
                    xs[4*q+0] = t.x; xs[4*q+1] = t.y; xs[4*q+2] = t.z; xs[4*q+3] = t.w;
                }
                const float4* pe = reinterpret_cast<const float4*>(ea_c + (size_t)e * ED);
#pragma unroll
                for (int q = 0; q < 2; q++) {
                    float4 t = pe[q];
                    ee[4*q+0] = t.x; ee[4*q+1] = t.y; ee[4*q+2] = t.z; ee[4*q+3] = t.w;
                }
            }
#pragma unroll
            for (int h = 0; h < HD; h++) {
                float t = gvb1[h];
#pragma unroll
                for (int i = 0; i < ND; i++) t = fmaf(xvr[i], gvW1[i * HD + h], t);
#pragma unroll
                for (int i = 0; i < ND; i++) t = fmaf(xs[i], gvW1[(ND + i) * HD + h], t);
#pragma unroll
                for (int i = 0; i < ED; i++) t = fmaf(ee[i], gvW1[(2 * ND + i) * HD + h], t);
                acc[h] += fmaxf(t, 0.f);
            }
        }
    }
#pragma unroll
    for (int m = 1; m < 8; m <<= 1) {
#pragma unroll
        for (int h = 0; h < HD; h++) acc[h] += __shfl_xor(acc[h], m, 64);
    }
    if (sub == 0) {
        float4* dst = reinterpret_cast<float4*>(Ag + (size_t)v * HD);
#pragma unroll
        for (int q = 0; q < 8; q++)
            dst[q] = make_float4(acc[4*q+0], acc[4*q+1], acc[4*q+2], acc[4*q+3]);
    }

    // ---------------- h: a2v edges ----------------
#pragma unroll
    for (int h = 0; h < HD; h++) acc[h] = 0.f;
    {
        int base = off_h[v], d = deg_h[v];
        for (int k = sub; k < d; k += 8) {
            int e = csr_h[base + k];
            int s = a2v_src[e];
            float xs[ND], ee[ED];
            {
                const float4* p = reinterpret_cast<const float4*>(xa + (size_t)s * ND);
#pragma unroll
                for (int q = 0; q < 4; q++) {
                    float4 t = p[q];
                    xs[4*q+0] = t.x; xs[4*q+1] = t.y; xs[4*q+2] = t.z; xs[4*q+3] = t.w;
                }
                const float4* pe = reinterpret_cast<const float4*>(ea_a + (size_t)e * ED);
#pragma unroll
                for (int q = 0; q < 2; q++) {
                    float4 t = pe[q];
                    ee[4*q+0] = t.x; ee[4*q+1] = t.y; ee[4*q+2] = t.z; ee[4*q+3] = t.w;
                }
            }
#pragma unroll
            for (int h = 0; h < HD; h++) {
                float t = hvb1[h];
#pragma unroll
                for (int i = 0; i < ND; i++) t = fmaf(xvr[i], hvW1[i * HD + h], t);
#pragma unroll
                for (int i = 0; i < ND; i++) t = fmaf(xs[i], hvW1[(ND + i) * HD + h], t);
#pragma unroll
                for (int i = 0; i < ED; i++) t = fmaf(ee[i], hvW1[(2 * ND + i) * HD + h], t);
                acc[h] += fmaxf(t, 0.f);
            }
        }
    }
#pragma unroll
    for (int m = 1; m < 8; m <<= 1) {
#pragma unroll
        for (int h = 0; h < HD; h++) acc[h] += __shfl_xor(acc[h], m, 64);
    }
    if (sub == 0) {
        float4* dst = reinterpret_cast<float4*>(Ah + (size_t)v * HD);
#pragma unroll
        for (int q = 0; q < 8; q++)
            dst[q] = make_float4(acc[4*q+0], acc[4*q+1], acc[4*q+2], acc[4*q+3]);
    }
}

// ===========================================================================
// fv node kernel: one thread per v.
//   hid[h] = relu(fvb1[h] + [dg>0]bg[h] + [dh>0]bh[h] + xv.fvW1[0:16]
//            + (Ag.Mg)[h]/max(dg,1) + (Ah.Mh)[h]/max(dh,1))
//   f_v = hid . fvW2 + fvb2
// ===========================================================================
__global__ __launch_bounds__(256) void fv_node_kernel(
    const float* __restrict__ xv,
    const float* __restrict__ Ag, const float* __restrict__ Ah,
    const int* __restrict__ deg_g, const int* __restrict__ deg_h,
    const float* __restrict__ fvW1, const float* __restrict__ fvb1,
    const float* __restrict__ fvW2, const float* __restrict__ fvb2,
    const float* __restrict__ Mg, const float* __restrict__ bg,
    const float* __restrict__ Mh, const float* __restrict__ bh,
    float* __restrict__ fv, int nV)
{
    int v = blockIdx.x * 256 + threadIdx.x;
    if (v >= nV) return;

    float xvr[ND], agr[HD], ahr[HD];
    {
        const float4* p = reinterpret_cast<const float4*>(xv + (size_t)v * ND);
#pragma unroll
        for (int q = 0; q < 4; q++) {
            float4 t = p[q];
            xvr[4*q+0] = t.x; xvr[4*q+1] = t.y; xvr[4*q+2] = t.z; xvr[4*q+3] = t.w;
        }
        const float4* pg = reinterpret_cast<const float4*>(Ag + (size_t)v * HD);
        const float4* ph = reinterpret_cast<const float4*>(Ah + (size_t)v * HD);
#pragma unroll
        for (int q = 0; q < 8; q++) {
            float4 t = pg[q];
            agr[4*q+0] = t.x; agr[4*q+1] = t.y; agr[4*q+2] = t.z; agr[4*q+3] = t.w;
            float4 u = ph[q];
            ahr[4*q+0] = u.x; ahr[4*q+1] = u.y; ahr[4*q+2] = u.z; ahr[4*q+3] = u.w;
        }
    }
    int dg = deg_g[v], dh = deg_h[v];
    float invg = dg > 0 ? 1.f / (float)dg : 0.f;
    float invh = dh > 0 ? 1.f / (float)dh : 0.f;
    float bgk  = dg > 0 ? 1.f : 0.f;
    float bhk  = dh > 0 ? 1.f : 0.f;

    float hid[HD];
#pragma unroll
    for (int h = 0; h < HD; h++) {
        float t = fvb1[h] + bgk * bg[h] + bhk * bh[h];
#pragma unroll
        for (int i = 0; i < ND; i++) t = fmaf(xvr[i], fvW1[i * HD + h], t);
        float sg = 0.f, sh = 0.f;
#pragma unroll
        for (int c = 0; c < HD; c++) {
            sg = fmaf(agr[c], Mg[c * HD + h], sg);
            sh = fmaf(ahr[c], Mh[c * HD + h], sh);
        }
        t += invg * sg + invh * sh;
        hid[h] = fmaxf(t, 0.f);
    }
    float* ob = fv + (size_t)v * HD;
#pragma unroll
    for (int o = 0; o < HD; o++) {
        float t = fvb2[o];
#pragma unroll
        for (int h = 0; h < HD; h++) t = fmaf(hid[h], fvW2[h * HD + o], t);
        ob[o] = t;
    }
}

// ===========================================================================
// ga edge kernel: one full wave (64 lanes) per cut node, edge-split.
// xa.W1 partial hoisted out of the edge loop.
// Writes Aga[a][32] = sum relu(ga layer1).
// ===========================================================================
__global__ __launch_bounds__(256) void ga_edge_kernel(
    const float* __restrict__ xa, const float* __restrict__ fvv,
    const float* __restrict__ ea_a,
    const int* __restrict__ a2v_tgt,
    const int* __restrict__ off_a, const int* __restrict__ deg_a, const int* __restrict__ csr_a,
    const float* __restrict__ gaW1, const float* __restrict__ gab1,
    float* __restrict__ Aga, int nA)
{
    int gid = blockIdx.x * 256 + threadIdx.x;
    int a   = gid >> 6;
    int ln  = threadIdx.x & 63;
    if (a >= nA) return;

    float xar[ND];
    {
        const float4* p = reinterpret_cast<const float4*>(xa + (size_t)a * ND);
#pragma unroll
        for (int q = 0; q < 4; q++) {
            float4 t = p[q];
            xar[4*q+0] = t.x; xar[4*q+1] = t.y; xar[4*q+2] = t.z; xar[4*q+3] = t.w;
        }
    }
    // node-invariant partial: px[h] = b1[h] + xa . W1[0:16]
    float px[HD];
#pragma unroll
    for (int h = 0; h < HD; h++) {
        float t = gab1[h];
#pragma unroll
        for (int i = 0; i < ND; i++) t = fmaf(xar[i], gaW1[i * HD + h], t);
        px[h] = t;
    }

    float acc[HD];
#pragma unroll
    for (int h = 0; h < HD; h++) acc[h] = 0.f;

    int base = off_a[a], d = deg_a[a];
    for (int k = ln; k < d; k += 64) {
        int e = csr_a[base + k];
        int t = a2v_tgt[e];
        float fvt[HD], ee[ED];
        {
            const float4* p = reinterpret_cast<const float4*>(fvv + (size_t)t * HD);
#pragma unroll
            for (int q = 0; q < 8; q++) {
                float4 w = p[q];
                fvt[4*q+0] = w.x; fvt[4*q+1] = w.y; fvt[4*q+2] = w.z; fvt[4*q+3] = w.w;
            }
            const float4* pe = reinterpret_cast<const float4*>(ea_a + (size_t)e * ED);
#pragma unroll
            for (int q = 0; q < 2; q++) {
                float4 w = pe[q];
                ee[4*q+0] = w.x; ee[4*q+1] = w.y; ee[4*q+2] = w.z; ee[4*q+3] = w.w;
            }
        }
#pragma unroll
        for (int h = 0; h < HD; h++) {
            float s = px[h];
#pragma unroll
            for (int i = 0; i < HD; i++) s = fmaf(fvt[i], gaW1[(ND + i) * HD + h], s);
#pragma unroll
            for (int i = 0; i < ED; i++) s = fmaf(ee[i], gaW1[(ND + HD + i) * HD + h], s);
            acc[h] += fmaxf(s, 0.f);
        }
    }
#pragma unroll
    for (int m = 1; m < 64; m <<= 1) {
#pragma unroll
        for (int h = 0; h < HD; h++) acc[h] += __shfl_xor(acc[h], m, 64);
    }
    if (ln == 0) {
        float4* dst = reinterpret_cast<float4*>(Aga + (size_t)a * HD);
#pragma unroll
        for (int q = 0; q < 8; q++)
            dst[q] = make_float4(acc[4*q+0], acc[4*q+1], acc[4*q+2], acc[4*q+3]);
    }
}

// ===========================================================================
// fa node kernel: one thread per a node -> final output.
// ===========================================================================
__global__ __launch_bounds__(256) void fa_node_kernel(
    const float* __restrict__ xa,
    const float* __restrict__ Aga, const int* __restrict__ deg_a,
    const float* __restrict__ faW1, const float* __restrict__ fab1,
    const float* __restrict__ faW2, const float* __restrict__ fab2,
    const float* __restrict__ Mga, const float* __restrict__ bga,
    float* __restrict__ out, int nA)
{
    int a = blockIdx.x * 256 + threadIdx.x;
    if (a >= nA) return;

    float xar[ND], agr[HD];
    {
        const float4* p = reinterpret_cast<const float4*>(xa + (size_t)a * ND);
#pragma unroll
        for (int q = 0; q < 4; q++) {
            float4 t = p[q];
            xar[4*q+0] = t.x; xar[4*q+1] = t.y; xar[4*q+2] = t.z; xar[4*q+3] = t.w;
        }
        const float4* pg = reinterpret_cast<const float4*>(Aga + (size_t)a * HD);
#pragma unroll
        for (int q = 0; q < 8; q++) {
            float4 t = pg[q];
            agr[4*q+0] = t.x; agr[4*q+1] = t.y; agr[4*q+2] = t.z; agr[4*q+3] = t.w;
        }
    }
    int d = deg_a[a];
    float inv = d > 0 ? 1.f / (float)d : 0.f;
    float bk  = d > 0 ? 1.f : 0.f;

    float hid[HD];
#pragma unroll
    for (int h = 0; h < HD; h++) {
        float t = fab1[h] + bk * bga[h];
#pragma unroll
        for (int i = 0; i < ND; i++) t = fmaf(xar[i], faW1[i * HD + h], t);
        float s = 0.f;
#pragma unroll
        for (int c = 0; c < HD; c++) s = fmaf(agr[c], Mga[c * HD + h], s);
        t += inv * s;
        hid[h] = fmaxf(t, 0.f);
    }
    float* ob = out + (size_t)a * HD;
#pragma unroll
    for (int o = 0; o < HD; o++) {
        float t = fab2[o];
#pragma unroll
        for (int h = 0; h < HD; h++) t = fmaf(hid[h], faW2[h * HD + o], t);
        ob[o] = t;
    }
}

// ===========================================================================
extern "C" void kernel_launch(void* const* d_in, const int* in_sizes, int n_in,
                              void* d_out, int out_size, void* d_ws, size_t ws_size,
                              hipStream_t stream) {
    const float* x_c    = (const float*)d_in[0];
    const float* x_v    = (const float*)d_in[1];
    const float* x_a    = (const float*)d_in[2];
    const int*   ei_c2v = (const int*)d_in[3];
    const int*   ei_a2v = (const int*)d_in[4];
    const float* ea_c2v = (const float*)d_in[5];
    const float* ea_a2v = (const float*)d_in[6];
    const float *gv_W1=(const float*)d_in[7],  *gv_b1=(const float*)d_in[8],
                *gv_W2=(const float*)d_in[9],  *gv_b2=(const float*)d_in[10];
    const float *hv_W1=(const float*)d_in[11], *hv_b1=(const float*)d_in[12],
                *hv_W2=(const float*)d_in[13], *hv_b2=(const float*)d_in[14];
    const float *fv_W1=(const float*)d_in[15], *fv_b1=(const float*)d_in[16],
                *fv_W2=(const float*)d_in[17], *fv_b2=(const float*)d_in[18];
    const float *ga_W1=(const float*)d_in[19], *ga_b1=(const float*)d_in[20],
                *ga_W2=(const float*)d_in[21], *ga_b2=(const float*)d_in[22];
    const float *fa_W1=(const float*)d_in[23], *fa_b1=(const float*)d_in[24],
                *fa_W2=(const float*)d_in[25], *fa_b2=(const float*)d_in[26];

    const int NV = in_sizes[1] / ND;
    const int NA = in_sizes[2] / ND;
    const int EC = in_sizes[3] / 2;
    const int EA = in_sizes[4] / 2;
    (void)n_in; (void)ws_size; (void)out_size;

    const int* c2v_s = ei_c2v;            // constraint side of c2v
    const int* c2v_t = ei_c2v + EC;       // variable side
    const int* a2v_s = ei_a2v;            // cut node side
    const int* a2v_t = ei_a2v + EA;       // variable side

    // Workspace layout (4B words)
    int* wsI = (int*)d_ws;
    int* deg_g = wsI;                 // NV
    int* deg_h = deg_g + NV;          // NV
    int* deg_a = deg_h + NV;          // NA
    int* off_g = deg_a + NA;          // NV
    int* off_h = off_g + NV;          // NV
    int* off_a = off_h + NV;          // NA
    int* cur_g = off_a + NA;          // NV
    int* cur_h = cur_g + NV;          // NV
    int* cur_a = cur_h + NV;          // NA
    int* csr_g = cur_a + NA;          // EC
    int* csr_h = csr_g + EC;          // EA
    int* csr_a = csr_h + EA;          // EA
    float* Ag  = (float*)(csr_a + EA);   // NV*HD
    float* Ah  = Ag + (size_t)NV * HD;   // NV*HD
    float* Aga = Ah + (size_t)NV * HD;   // NA*HD
    float* f_v = Aga + (size_t)NA * HD;  // NV*HD
    float* Mg  = f_v + (size_t)NV * HD;  // 1024
    float* Mh  = Mg + HD * HD;           // 1024
    float* Mga = Mh + HD * HD;           // 1024
    float* bgv = Mga + HD * HD;          // 32
    float* bhv = bgv + HD;               // 32
    float* bgav= bhv + HD;               // 32

    // zero the degree histograms only
    hipMemsetAsync(deg_g, 0, (size_t)(2 * NV + NA) * sizeof(int), stream);

    // folded layer-2 matrices (independent of CSR)
    precomp_kernel<<<1, 256, 0, stream>>>(gv_W2, gv_b2, hv_W2, hv_b2, ga_W2, ga_b2,
                                          fv_W1, fa_W1, Mg, bgv, Mh, bhv, Mga, bgav);

    // histograms
    hist_kernel<<<(EC + 255) / 256, 256, 0, stream>>>(c2v_t, deg_g, EC);
    hist_kernel<<<(EA + 255) / 256, 256, 0, stream>>>(a2v_t, deg_h, EA);
    hist_kernel<<<(EA + 255) / 256, 256, 0, stream>>>(a2v_s, deg_a, EA);

    // exclusive scans (3 arrays, 1 block each)
    scan3_kernel<<<3, 1024, 0, stream>>>(deg_g, off_g, cur_g, NV,
                                         deg_h, off_h, cur_h, NV,
                                         deg_a, off_a, cur_a, NA);

    // scatter edge ids into CSR
    scatter_kernel<<<(EC + 255) / 256, 256, 0, stream>>>(c2v_t, cur_g, csr_g, EC);
    scatter_kernel<<<(EA + 255) / 256, 256, 0, stream>>>(a2v_t, cur_h, csr_h, EA);
    scatter_kernel<<<(EA + 255) / 256, 256, 0, stream>>>(a2v_s, cur_a, csr_a, EA);

    // variable-node edge aggregation (8 lanes/node)
    fv_edge_kernel<<<(NV * 8 + 255) / 256, 256, 0, stream>>>(
        x_v, x_c, x_a, c2v_s, a2v_s, ea_c2v, ea_a2v,
        off_g, deg_g, csr_g, off_h, deg_h, csr_h,
        gv_W1, gv_b1, hv_W1, hv_b1, Ag, Ah, NV);

    // variable-node MLP -> f_v
    fv_node_kernel<<<(NV + 255) / 256, 256, 0, stream>>>(
        x_v, Ag, Ah, deg_g, deg_h,
        fv_W1, fv_b1, fv_W2, fv_b2, Mg, bgv, Mh, bhv, f_v, NV);

    // cut-node edge aggregation (64 lanes/node)
    ga_edge_kernel<<<(NA * 64 + 255) / 256, 256, 0, stream>>>(
        x_a, f_v, ea_a2v, a2v_t,
        off_a, deg_a, csr_a, ga_W1, ga_b1, Aga, NA);

    // cut-node MLP -> output
    fa_node_kernel<<<(NA + 255) / 256, 256, 0, stream>>>(
        x_a, Aga, deg_a,
        fa_W1, fa_b1, fa_W2, fa_b2, Mga, bgav, (float*)d_out, NA);
}